// Round 3
// baseline (267.195 us; speedup 1.0000x reference)
//
#include <hip/hip_runtime.h>

// EnhancedMemoryStack: B=32768, S=16, D=64. fp32 I/O; bf16 MFMA internally.
//
// Algebra:
//   scores = xhat (Q K^T) xhat^T = xhat M xhat^T, M (128x128) precomputed once.
//   z_read = sum_t w[t] vhat[t],  w[t] = sum_s (np[s]/rowsum[s]) e[s][t]  (softmax folded)
// Round-3 structure: 2 batches per wave iteration (shared weight-fragment loads,
// 2x chain ILP), next-pair global loads prefetched under compute, S^T softmax
// (operand-swapped MFMA so row s lives in lane c = np's lane), v_exp/v_rcp fast paths.
//
// 512-thr WG (8 waves): LDS = M(32K) + Wv(16K) + 8 waves x dual 4K SY = 112K -> 1 WG/CU.
// d_ws: [0..4) active-slot counter, [1024..33792) M^T bf16.

typedef __bf16 bf16x8 __attribute__((ext_vector_type(8)));
typedef float  f32x4  __attribute__((ext_vector_type(4)));
typedef float  f4     __attribute__((ext_vector_type(4)));

#define B_TOT   32768
#define GRID_WG 512
#define NWAVES  4096
#define LOG2E   1.4426950408889634f

__device__ __forceinline__ unsigned short f2bf(float x) {
  __bf16 h = (__bf16)x;
  return __builtin_bit_cast(unsigned short, h);
}
__device__ __forceinline__ float rcp_f(float x) { return __builtin_amdgcn_rcpf(x); }
__device__ __forceinline__ float ex2_f(float x) { return __builtin_amdgcn_exp2f(x); }
__device__ __forceinline__ float sigm(float x) { return rcp_f(1.0f + ex2_f(-LOG2E * x)); }

__global__ void ems_fin(const unsigned int* __restrict__ c, float* __restrict__ out) {
  if (threadIdx.x == 0) out[0] = (float)(*c) * (1.0f / 32768.0f);
}

// Mt[e2][e] = sum_{E'} Q[e][E'] K[e2][E'];  also zeroes the active-slot counter.
__global__ void __launch_bounds__(128)
ems_mt(const float* __restrict__ wqr, const float* __restrict__ wqi,
       const float* __restrict__ wkr, const float* __restrict__ wki,
       unsigned short* __restrict__ mt, unsigned int* __restrict__ cnt)
{
  if (blockIdx.x == 0 && threadIdx.x == 0) *cnt = 0u;
  __shared__ float sK[128];
  const int e2 = (int)blockIdx.x;
  const int e  = (int)threadIdx.x;
  float kv;
  if (e < 64) kv = (e2 < 64) ? wkr[e*64 + e2]      : -wki[e*64 + (e2-64)];
  else        kv = (e2 < 64) ? wki[(e-64)*64 + e2] :  wkr[(e-64)*64 + (e2-64)];
  sK[e] = kv;
  __syncthreads();
  float acc = 0.0f;
  #pragma unroll 8
  for (int Ep = 0; Ep < 64; ++Ep) {
    float q = (e < 64) ? wqr[Ep*64 + e] : -wqi[Ep*64 + (e-64)];
    acc += q * sK[Ep];
  }
  #pragma unroll 8
  for (int Ep = 0; Ep < 64; ++Ep) {
    float q = (e < 64) ? wqi[Ep*64 + e] : wqr[Ep*64 + (e-64)];
    acc += q * sK[64 + Ep];
  }
  mt[e2*128 + e] = f2bf(acc);
}

__global__ void __launch_bounds__(512, 2)
ems_main(const float* __restrict__ z_real, const float* __restrict__ z_imag,
         const float* __restrict__ mem,    const float* __restrict__ ptrv,
         const float* __restrict__ ctrl,
         const float* __restrict__ wvr,    const float* __restrict__ wvi,
         const unsigned short* __restrict__ mt,
         float* __restrict__ out_zr, float* __restrict__ out_zi,
         float* __restrict__ out_mem, float* __restrict__ out_ptr,
         unsigned int* __restrict__ ws_cnt)
{
  // [0..16384)     Mt bf16 [e2][e], 16B-chunk swizzle: chunk ^ (e2&15)
  // [16384..24576) Wv_r, Wv_i bf16 [e][d], chunk ^ (e&7)
  // [24576..57344) per-wave DUAL y-stage: 2 x [16][128] bf16, chunk ^ (row&15)
  __shared__ __align__(16) unsigned short lds[57344];

  const int tid = (int)threadIdx.x;

  for (int idx = tid; idx < 16384; idx += 512) {
    int e2 = idx >> 7, e = idx & 127;
    lds[(e2 << 7) + (((e >> 3) ^ (e2 & 15)) << 3) + (e & 7)] = mt[idx];
  }
  #pragma unroll
  for (int m = 0; m < 2; ++m) {
    const float* wp = m ? wvi : wvr;
    for (int idx = tid; idx < 4096; idx += 512) {
      int e = idx >> 6, d = idx & 63;
      lds[16384 + (m << 12) + (e << 6) + (((d >> 3) ^ (e & 7)) << 3) + (d & 7)] = f2bf(wp[idx]);
    }
  }
  __syncthreads();

  const int lane = tid & 63;
  const int wv   = tid >> 6;
  const int c    = lane & 15;
  const int g    = lane >> 4;

  unsigned short* SYp[2];
  SYp[0] = &lds[24576 + (wv << 12)];
  SYp[1] = SYp[0] + 2048;

  const f4* mem4 = (const f4*)mem;
  const f4* zr4  = (const f4*)z_real;
  const f4* zi4  = (const f4*)z_imag;
  f4* omem4 = (f4*)out_mem;

  f4 cm[2][8], cz[2][8];
  float pmv[2], ppv[2], pcv[2], ct0[2], ct1[2], ct2[2];

  auto loadB = [&](int b, int q) {
    #pragma unroll
    for (int t4 = 0; t4 < 4; ++t4) {
      int i4 = b*512 + c*32 + t4*8 + g*2;
      cm[q][2*t4]   = mem4[i4];
      cm[q][2*t4+1] = mem4[i4+1];
    }
    int zb = b*16 + g*2;
    cz[q][0] = zr4[zb];   cz[q][1] = zr4[zb+1];
    cz[q][2] = zr4[zb+8]; cz[q][3] = zr4[zb+9];
    cz[q][4] = zi4[zb];   cz[q][5] = zi4[zb+1];
    cz[q][6] = zi4[zb+8]; cz[q][7] = zi4[zb+9];
    pmv[q] = ptrv[b*16 + ((c+15)&15)];
    ppv[q] = ptrv[b*16 + ((c+ 1)&15)];
    pcv[q] = ptrv[b*16 + c];
    ct0[q] = ctrl[b*3+0]; ct1[q] = ctrl[b*3+1]; ct2[q] = ctrl[b*3+2];
  };

  unsigned int active_acc = 0u;
  const int b0 = (int)blockIdx.x * 8 + wv;
  int bq[2];
  bq[0] = b0;
  bq[1] = b0 + NWAVES;
  loadB(bq[0], 0);
  loadB(bq[1], 1);

  #pragma unroll 1
  for (int p = 0; p < 4; ++p) {
    int bcur[2] = { bq[0], bq[1] };

    // ---------- gates + pointer update (both batches) ----------
    float npv[2], puv[2], ompv[2];
    #pragma unroll
    for (int q = 0; q < 2; ++q) {
      float pu = sigm(ct0[q]);
      float po = sigm(ct1[q]);
      float st = sigm(ct2[q]);
      float rt = rcp_f(pu + po + st + 1e-6f);
      pu *= rt; po *= rt; st *= rt;
      float np = pu*pmv[q] + po*ppv[q] + st*pcv[q];
      if (g == 0) out_ptr[bcur[q]*16 + c] = np;
      unsigned long long ball = __ballot(np > 0.1f);
      active_acc += (unsigned int)__popcll(ball & 0xFFFFull);
      npv[q] = np; puv[q] = pu; ompv[q] = 1.0f - pu;
    }

    // ---------- mem_new (fp32 exact, NT store) + xhat fragments ----------
    bf16x8 af[2][4], afn[2][2];
    #pragma unroll
    for (int q = 0; q < 2; ++q) {
      float pu = puv[q], om = ompv[q];
      #pragma unroll
      for (int t4 = 0; t4 < 4; ++t4) {
        f4 r0 = cm[q][2*t4]   * om + pu * cz[q][2*t4];
        f4 r1 = cm[q][2*t4+1] * om + pu * cz[q][2*t4+1];
        int i4 = bcur[q]*512 + c*32 + t4*8 + g*2;
        __builtin_nontemporal_store(r0, &omem4[i4]);
        __builtin_nontemporal_store(r1, &omem4[i4+1]);
        #pragma unroll
        for (int k = 0; k < 4; ++k) {
          af[q][t4][k]   = (__bf16)r0[k];
          af[q][t4][4+k] = (__bf16)r1[k];
        }
        if (t4 >= 2) {
          #pragma unroll
          for (int k = 0; k < 4; ++k) {
            afn[q][t4-2][k]   = (__bf16)(-r0[k]);
            afn[q][t4-2][4+k] = (__bf16)(-r1[k]);
          }
        }
      }
    }

    // ---------- prefetch next pair (hidden under y/scores/softmax/vhat) ----------
    if (p < 3) {
      loadB(bcur[0] + 2*NWAVES, 0);
      loadB(bcur[1] + 2*NWAVES, 1);
    }

    // ---------- y = xhat * M (shared Mt fragments), stage transposed ----------
    #pragma unroll
    for (int n2 = 0; n2 < 8; ++n2) {
      int e2 = (n2 << 4) + c;
      f32x4 acc0 = {0.f,0.f,0.f,0.f}, acc1 = {0.f,0.f,0.f,0.f};
      #pragma unroll
      for (int t = 0; t < 4; ++t) {
        bf16x8 bm = *(const bf16x8*)&lds[(e2 << 7) + ((((t << 2) + g) ^ c) << 3)];
        acc0 = __builtin_amdgcn_mfma_f32_16x16x32_bf16(af[0][t], bm, acc0, 0,0,0);
        acc1 = __builtin_amdgcn_mfma_f32_16x16x32_bf16(af[1][t], bm, acc1, 0,0,0);
      }
      int chb = (n2 << 1) | (c >> 3);
      #pragma unroll
      for (int i = 0; i < 4; ++i) {
        int s = (g << 2) + i;
        int off = (s << 7) + ((chb ^ s) << 3) + (c & 7);
        SYp[0][off] = f2bf(acc0[i]);
        SYp[1][off] = f2bf(acc1[i]);
      }
    }

    // ---------- S^T = xhat . y^T (operand-swapped): lane(c,g) holds S[s=c][t=4g+i] ----------
    f32x4 sc0 = {0.f,0.f,0.f,0.f}, sc1 = {0.f,0.f,0.f,0.f};
    #pragma unroll
    for (int t = 0; t < 4; ++t) {
      int off = (c << 7) + ((((t << 2) + g) ^ c) << 3);
      bf16x8 y0 = *(const bf16x8*)&SYp[0][off];
      bf16x8 y1 = *(const bf16x8*)&SYp[1][off];
      sc0 = __builtin_amdgcn_mfma_f32_16x16x32_bf16(af[0][t], y0, sc0, 0,0,0);
      sc1 = __builtin_amdgcn_mfma_f32_16x16x32_bf16(af[1][t], y1, sc1, 0,0,0);
    }

    // ---------- softmax (no max-shift; |s|<~12 by construction) + fold np ----------
    // e = exp2(s * 0.125*log2e); r = rowsum (local4 + xor16 + xor32);
    // u = np * rcp(r); w[t=4g+i] = sum_c u*e  (xor 1,2,4,8)
    float w4[2][4];
    #pragma unroll
    for (int q = 0; q < 2; ++q) {
      f32x4 scq = q ? sc1 : sc0;
      float e0 = ex2_f(scq[0] * 0.18033688011112042f);
      float e1 = ex2_f(scq[1] * 0.18033688011112042f);
      float e2 = ex2_f(scq[2] * 0.18033688011112042f);
      float e3 = ex2_f(scq[3] * 0.18033688011112042f);
      float r = (e0 + e1) + (e2 + e3);
      r += __shfl_xor(r, 16, 64);
      r += __shfl_xor(r, 32, 64);
      float u = npv[q] * rcp_f(r);
      float v0 = u*e0, v1 = u*e1, v2 = u*e2, v3 = u*e3;
      #pragma unroll
      for (int d = 1; d <= 8; d <<= 1) {
        v0 += __shfl_xor(v0, d, 64);
        v1 += __shfl_xor(v1, d, 64);
        v2 += __shfl_xor(v2, d, 64);
        v3 += __shfl_xor(v3, d, 64);
      }
      w4[q][0] = v0; w4[q][1] = v1; w4[q][2] = v2; w4[q][3] = v3;
    }

    // ---------- vhat (shared Wv fragments) + weighted readout ----------
    #pragma unroll
    for (int n = 0; n < 4; ++n) {
      int eb = 16384 + (((n << 4) + c) << 6);
      int e7 = c & 7;
      f32x4 ar0 = {0.f,0.f,0.f,0.f}, ai0 = {0.f,0.f,0.f,0.f};
      f32x4 ar1 = {0.f,0.f,0.f,0.f}, ai1 = {0.f,0.f,0.f,0.f};
      #pragma unroll
      for (int t = 0; t < 2; ++t) {
        int ch = (((t << 2) + g) ^ e7) << 3;
        bf16x8 fr = *(const bf16x8*)&lds[eb + ch];
        bf16x8 fi = *(const bf16x8*)&lds[eb + 4096 + ch];
        ar0 = __builtin_amdgcn_mfma_f32_16x16x32_bf16(af[0][t],   fr, ar0, 0,0,0);
        ar1 = __builtin_amdgcn_mfma_f32_16x16x32_bf16(af[1][t],   fr, ar1, 0,0,0);
        ai0 = __builtin_amdgcn_mfma_f32_16x16x32_bf16(af[0][t],   fi, ai0, 0,0,0);
        ai1 = __builtin_amdgcn_mfma_f32_16x16x32_bf16(af[1][t],   fi, ai1, 0,0,0);
        ar0 = __builtin_amdgcn_mfma_f32_16x16x32_bf16(afn[0][t],  fi, ar0, 0,0,0);
        ar1 = __builtin_amdgcn_mfma_f32_16x16x32_bf16(afn[1][t],  fi, ar1, 0,0,0);
        ai0 = __builtin_amdgcn_mfma_f32_16x16x32_bf16(af[0][t+2], fr, ai0, 0,0,0);
        ai1 = __builtin_amdgcn_mfma_f32_16x16x32_bf16(af[1][t+2], fr, ai1, 0,0,0);
      }
      #pragma unroll
      for (int q = 0; q < 2; ++q) {
        f32x4 arq = q ? ar1 : ar0;
        f32x4 aiq = q ? ai1 : ai0;
        float prr = arq[0]*w4[q][0] + arq[1]*w4[q][1] + arq[2]*w4[q][2] + arq[3]*w4[q][3];
        float pri = aiq[0]*w4[q][0] + aiq[1]*w4[q][1] + aiq[2]*w4[q][2] + aiq[3]*w4[q][3];
        prr += __shfl_xor(prr, 16, 64);
        prr += __shfl_xor(prr, 32, 64);
        pri += __shfl_xor(pri, 16, 64);
        pri += __shfl_xor(pri, 32, 64);
        if (g == 0) {
          out_zr[bcur[q]*64 + (n << 4) + c] = prr;
          out_zi[bcur[q]*64 + (n << 4) + c] = pri;
        }
      }
    }

    bq[0] = bcur[0] + 2*NWAVES;
    bq[1] = bcur[1] + 2*NWAVES;
  }

  if (lane == 0) atomicAdd(ws_cnt, active_acc);
}

extern "C" void kernel_launch(void* const* d_in, const int* in_sizes, int n_in,
                              void* d_out, int out_size, void* d_ws, size_t ws_size,
                              hipStream_t stream) {
  const float* z_real = (const float*)d_in[0];
  const float* z_imag = (const float*)d_in[1];
  const float* memp   = (const float*)d_in[2];
  const float* ptrv   = (const float*)d_in[3];
  const float* ctrl   = (const float*)d_in[4];
  const float* wq_r   = (const float*)d_in[5];
  const float* wq_i   = (const float*)d_in[6];
  const float* wk_r   = (const float*)d_in[7];
  const float* wk_i   = (const float*)d_in[8];
  const float* wv_r   = (const float*)d_in[9];
  const float* wv_i   = (const float*)d_in[10];

  float* out     = (float*)d_out;
  float* out_zr  = out;
  float* out_zi  = out + 2097152;
  float* out_mem = out + 4194304;
  float* out_ptr = out + 71303168;
  float* out_sc  = out + 71827456;

  unsigned int*   cnt = (unsigned int*)d_ws;
  unsigned short* mt  = (unsigned short*)((char*)d_ws + 1024);  // needs ws_size >= 33792

  ems_mt<<<128, 128, 0, stream>>>(wq_r, wq_i, wk_r, wk_i, mt, cnt);
  ems_main<<<GRID_WG, 512, 0, stream>>>(z_real, z_imag, memp, ptrv, ctrl,
                                        wv_r, wv_i, mt,
                                        out_zr, out_zi, out_mem, out_ptr, cnt);
  ems_fin<<<1, 64, 0, stream>>>(cnt, out_sc);
}

// Round 4
// 150.735 us; speedup vs baseline: 1.7726x; 1.7726x over previous
//
#include <hip/hip_runtime.h>

// EnhancedMemoryStack: B=32768, S=16, D=64. fp32 I/O; bf16 MFMA internally.
//
// Algebra:
//   scores = xhat (Q K^T) xhat^T = xhat M xhat^T, with M = Q K^T (128x128) precomputed.
//   z_read = sum_t w[t] vhat[t],  w[t] = sum_s (np[s]/rowsum[s]) e[s][t]  (softmax folded)
//
// R4 structure (revert to R2 skeleton, 64-VGPR class, + chain surgery):
//   - y-MFMA computed as mfma(A=Mt_frag, B=xhat_frag): C gives each lane 4 CONTIGUOUS
//     y columns of row s=c -> SY staged with 8 ds_write_b64 (was 32 ds_write_b16).
//   - scores as mfma(A=xhat, B=y_rowc_frag) -> S^T layout: lane(c,g) holds S[s=c][t=4g+i],
//     so np (indexed by s=c) needs no broadcast.
//   - fast softmax: no max-shift (|s|<~16), v_exp2/v_rcp, norm+ptr folded: u=np*rcp(r).
//   - per-WG LDS count reduction -> 1 global atomic per WG.
//
// 512-thr WG (8 waves, 1 batch each/iter): LDS = M(32K)+Wv(16K)+8x4K SY = 80KB -> 2 WG/CU.
// d_ws: [0..4) active-slot counter, [1024..33792) M^T bf16 (needs ws_size >= 33792).

typedef __bf16 bf16x8 __attribute__((ext_vector_type(8)));
typedef float  f32x4  __attribute__((ext_vector_type(4)));
typedef float  f4     __attribute__((ext_vector_type(4)));

#define B_TOT   32768
#define GRID_WG 512
#define NWAVES  4096
#define BPW     8
#define LOG2E   1.4426950408889634f
#define EXSC    0.18033688011112042f   // 0.125 * log2(e)

__device__ __forceinline__ unsigned short f2bf(float x) {
  __bf16 h = (__bf16)x;
  return __builtin_bit_cast(unsigned short, h);
}
__device__ __forceinline__ float rcp_f(float x) { return __builtin_amdgcn_rcpf(x); }
__device__ __forceinline__ float ex2_f(float x) { return __builtin_amdgcn_exp2f(x); }
__device__ __forceinline__ float sigm(float x) { return rcp_f(1.0f + ex2_f(-LOG2E * x)); }

__global__ void ems_fin(const unsigned int* __restrict__ c, float* __restrict__ out) {
  if (threadIdx.x == 0) out[0] = (float)(*c) * (1.0f / 32768.0f);
}

// Mt[e2][e] = sum_{E'} Q[e][E'] K[e2][E']; also zeroes the active-slot counter.
__global__ void __launch_bounds__(128)
ems_mt(const float* __restrict__ wqr, const float* __restrict__ wqi,
       const float* __restrict__ wkr, const float* __restrict__ wki,
       unsigned short* __restrict__ mt, unsigned int* __restrict__ cnt)
{
  if (blockIdx.x == 0 && threadIdx.x == 0) *cnt = 0u;
  __shared__ float sK[128];
  const int e2 = (int)blockIdx.x;
  const int e  = (int)threadIdx.x;
  float kv;
  if (e < 64) kv = (e2 < 64) ? wkr[e*64 + e2]      : -wki[e*64 + (e2-64)];
  else        kv = (e2 < 64) ? wki[(e-64)*64 + e2] :  wkr[(e-64)*64 + (e2-64)];
  sK[e] = kv;
  __syncthreads();
  float acc = 0.0f;
  #pragma unroll 8
  for (int Ep = 0; Ep < 64; ++Ep) {
    float q = (e < 64) ? wqr[Ep*64 + e] : -wqi[Ep*64 + (e-64)];
    acc += q * sK[Ep];
  }
  #pragma unroll 8
  for (int Ep = 0; Ep < 64; ++Ep) {
    float q = (e < 64) ? wqi[Ep*64 + e] : wqr[Ep*64 + (e-64)];
    acc += q * sK[64 + Ep];
  }
  mt[e2*128 + e] = f2bf(acc);
}

__global__ void __launch_bounds__(512, 4)
ems_main(const float* __restrict__ z_real, const float* __restrict__ z_imag,
         const float* __restrict__ mem,    const float* __restrict__ ptrv,
         const float* __restrict__ ctrl,
         const float* __restrict__ wvr,    const float* __restrict__ wvi,
         const unsigned short* __restrict__ mt,
         float* __restrict__ out_zr, float* __restrict__ out_zi,
         float* __restrict__ out_mem, float* __restrict__ out_ptr,
         unsigned int* __restrict__ ws_cnt)
{
  // [0..16384)     Mt bf16 [e2=128][e=128], 16B-chunk swizzle: chunk ^ (e2&15)
  // [16384..24576) Wv_r, Wv_i bf16 [e][d], 16B-chunk ^ (e&7)
  // [24576..40960) per-wave SY: y[s=16][e2=128] bf16, 16B-chunk ^ s
  __shared__ __align__(16) unsigned short lds[40960];

  const int tid = (int)threadIdx.x;

  for (int idx = tid; idx < 16384; idx += 512) {
    int e2 = idx >> 7, e = idx & 127;
    lds[(e2 << 7) + (((e >> 3) ^ (e2 & 15)) << 3) + (e & 7)] = mt[idx];
  }
  #pragma unroll
  for (int m = 0; m < 2; ++m) {
    const float* wp = m ? wvi : wvr;
    for (int idx = tid; idx < 4096; idx += 512) {
      int e = idx >> 6, d = idx & 63;
      lds[16384 + (m << 12) + (e << 6) + (((d >> 3) ^ (e & 7)) << 3) + (d & 7)] = f2bf(wp[idx]);
    }
  }
  __syncthreads();

  const int lane = tid & 63;
  const int wv   = tid >> 6;
  const int c    = lane & 15;   // MFMA A/B index; also slot s for S^T rows
  const int g    = lane >> 4;   // k-chunk group / C-row group

  unsigned short* SY = &lds[24576 + (wv << 11)];

  const f4* mem4 = (const f4*)mem;
  const f4* zr4  = (const f4*)z_real;
  const f4* zi4  = (const f4*)z_imag;
  f4* omem4 = (f4*)out_mem;

  unsigned int active_acc = 0u;
  const int b0 = (int)blockIdx.x * 8 + wv;

  for (int it = 0; it < BPW; ++it) {
    const int b = b0 + it * NWAVES;

    // ---------- global loads ----------
    f4 cm[8], cz[8];
    #pragma unroll
    for (int t4 = 0; t4 < 4; ++t4) {
      int i4 = b*512 + c*32 + t4*8 + g*2;
      cm[2*t4]   = mem4[i4];
      cm[2*t4+1] = mem4[i4+1];
    }
    {
      int zb = b*16 + g*2;
      cz[0] = zr4[zb];   cz[1] = zr4[zb+1];
      cz[2] = zr4[zb+8]; cz[3] = zr4[zb+9];
      cz[4] = zi4[zb];   cz[5] = zi4[zb+1];
      cz[6] = zi4[zb+8]; cz[7] = zi4[zb+9];
    }

    // ---------- gates + pointer update ----------
    float pu = sigm(ctrl[b*3+0]);
    float po = sigm(ctrl[b*3+1]);
    float st = sigm(ctrl[b*3+2]);
    float rt = rcp_f(pu + po + st + 1e-6f);
    pu *= rt; po *= rt; st *= rt;

    float pm = ptrv[b*16 + ((c+15)&15)];
    float pp = ptrv[b*16 + ((c+ 1)&15)];
    float pc = ptrv[b*16 + c];
    float np = pu*pm + po*pp + st*pc;    // new_ptr for slot s=c
    if (g == 0) out_ptr[b*16 + c] = np;
    unsigned long long ball = __ballot(np > 0.1f);
    active_acc += (unsigned int)__popcll(ball & 0xFFFFull);

    // ---------- mem_new (fp32 exact) + xhat fragments ----------
    float om = 1.0f - pu;
    bf16x8 af[4], afn[2];
    #pragma unroll
    for (int t4 = 0; t4 < 4; ++t4) {
      f4 r0 = cm[2*t4]   * om + pu * cz[2*t4];
      f4 r1 = cm[2*t4+1] * om + pu * cz[2*t4+1];
      int i4 = b*512 + c*32 + t4*8 + g*2;
      omem4[i4]   = r0;
      omem4[i4+1] = r1;
      #pragma unroll
      for (int k = 0; k < 4; ++k) {
        af[t4][k]   = (__bf16)r0[k];
        af[t4][4+k] = (__bf16)r1[k];
      }
      if (t4 >= 2) {
        #pragma unroll
        for (int k = 0; k < 4; ++k) {
          afn[t4-2][k]   = (__bf16)(-r0[k]);
          afn[t4-2][4+k] = (__bf16)(-r1[k]);
        }
      }
    }

    // ---------- y = xhat*M via yT-direction MFMA: lane gets 4 contiguous cols ----------
    // acc[i] = y[s=c][e2 = n2*16 + 4g + i]  -> one packed ds_write_b64 per n2
    #pragma unroll
    for (int n2 = 0; n2 < 8; ++n2) {
      int e2 = (n2 << 4) + c;
      f32x4 acc = {0.f,0.f,0.f,0.f};
      #pragma unroll
      for (int T = 0; T < 4; ++T) {
        bf16x8 am = *(const bf16x8*)&lds[(e2 << 7) + ((((T << 2) + g) ^ c) << 3)];
        acc = __builtin_amdgcn_mfma_f32_16x16x32_bf16(am, af[T], acc, 0, 0, 0);
      }
      uint2 pk;
      pk.x = (unsigned)f2bf(acc[0]) | ((unsigned)f2bf(acc[1]) << 16);
      pk.y = (unsigned)f2bf(acc[2]) | ((unsigned)f2bf(acc[3]) << 16);
      // chunk q = 2*n2 + (g>>1), half (g&1); swizzled pos q ^ c
      *(uint2*)&SY[(c << 7) + ((((n2 << 1) + (g >> 1)) ^ c) << 3) + ((g & 1) << 2)] = pk;
    }

    // ---------- S^T = xhat . y^T: lane(c,g) holds S[s=c][t=4g+i] ----------
    f32x4 sc = {0.f,0.f,0.f,0.f};
    #pragma unroll
    for (int T = 0; T < 4; ++T) {
      bf16x8 yb = *(const bf16x8*)&SY[(c << 7) + ((((T << 2) + g) ^ c) << 3)];
      sc = __builtin_amdgcn_mfma_f32_16x16x32_bf16(af[T], yb, sc, 0, 0, 0);
    }

    // ---------- fast softmax + fold np: w[t] = sum_s (np[s]/r[s]) e[s][t] ----------
    float e0 = ex2_f(sc[0] * EXSC);
    float e1 = ex2_f(sc[1] * EXSC);
    float e2v = ex2_f(sc[2] * EXSC);
    float e3 = ex2_f(sc[3] * EXSC);
    float r = (e0 + e1) + (e2v + e3);
    r += __shfl_xor(r, 16, 64);
    r += __shfl_xor(r, 32, 64);          // row-sum over all 16 t
    float u = np * rcp_f(r);             // np for s=c is lane-local
    float v0 = u*e0, v1 = u*e1, v2 = u*e2v, v3 = u*e3;
    #pragma unroll
    for (int d = 1; d <= 8; d <<= 1) {
      v0 += __shfl_xor(v0, d, 64);
      v1 += __shfl_xor(v1, d, 64);
      v2 += __shfl_xor(v2, d, 64);
      v3 += __shfl_xor(v3, d, 64);
    }
    float w4[4] = { v0, v1, v2, v3 };    // w[t = 4g+i]

    // ---------- vhat + weighted readout ----------
    #pragma unroll
    for (int n = 0; n < 4; ++n) {
      int eb = 16384 + (((n << 4) + c) << 6);
      int e7 = c & 7;
      f32x4 ar = {0.f,0.f,0.f,0.f}, ai = {0.f,0.f,0.f,0.f};
      #pragma unroll
      for (int t = 0; t < 2; ++t) {
        int ch = (((t << 2) + g) ^ e7) << 3;
        bf16x8 fr = *(const bf16x8*)&lds[eb + ch];
        bf16x8 fi = *(const bf16x8*)&lds[eb + 4096 + ch];
        ar = __builtin_amdgcn_mfma_f32_16x16x32_bf16(af[t],   fr, ar, 0,0,0);
        ai = __builtin_amdgcn_mfma_f32_16x16x32_bf16(af[t],   fi, ai, 0,0,0);
        ar = __builtin_amdgcn_mfma_f32_16x16x32_bf16(afn[t],  fi, ar, 0,0,0);
        ai = __builtin_amdgcn_mfma_f32_16x16x32_bf16(af[t+2], fr, ai, 0,0,0);
      }
      float prr = ar[0]*w4[0] + ar[1]*w4[1] + ar[2]*w4[2] + ar[3]*w4[3];
      float pri = ai[0]*w4[0] + ai[1]*w4[1] + ai[2]*w4[2] + ai[3]*w4[3];
      prr += __shfl_xor(prr, 16, 64);
      prr += __shfl_xor(prr, 32, 64);
      pri += __shfl_xor(pri, 16, 64);
      pri += __shfl_xor(pri, 32, 64);
      if (g == 0) out_zr[b*64 + (n << 4) + c] = prr;
      if (g == 1) out_zi[b*64 + (n << 4) + c] = pri;
    }
  }

  // ---------- per-WG reduction of active-slot count, 1 atomic per WG ----------
  __syncthreads();                        // all SY use done
  unsigned int* cnt_lds = (unsigned int*)&lds[24576];
  if (tid == 0) *cnt_lds = 0u;
  __syncthreads();
  if (lane == 0) atomicAdd(cnt_lds, active_acc);
  __syncthreads();
  if (tid == 0) atomicAdd(ws_cnt, *cnt_lds);
}

extern "C" void kernel_launch(void* const* d_in, const int* in_sizes, int n_in,
                              void* d_out, int out_size, void* d_ws, size_t ws_size,
                              hipStream_t stream) {
  const float* z_real = (const float*)d_in[0];
  const float* z_imag = (const float*)d_in[1];
  const float* memp   = (const float*)d_in[2];
  const float* ptrv   = (const float*)d_in[3];
  const float* ctrl   = (const float*)d_in[4];
  const float* wq_r   = (const float*)d_in[5];
  const float* wq_i   = (const float*)d_in[6];
  const float* wk_r   = (const float*)d_in[7];
  const float* wk_i   = (const float*)d_in[8];
  const float* wv_r   = (const float*)d_in[9];
  const float* wv_i   = (const float*)d_in[10];

  float* out     = (float*)d_out;
  float* out_zr  = out;
  float* out_zi  = out + 2097152;
  float* out_mem = out + 4194304;
  float* out_ptr = out + 71303168;
  float* out_sc  = out + 71827456;

  unsigned int*   cnt = (unsigned int*)d_ws;
  unsigned short* mtp = (unsigned short*)((char*)d_ws + 1024);  // ws_size >= 33792

  ems_mt<<<128, 128, 0, stream>>>(wq_r, wq_i, wk_r, wk_i, mtp, cnt);
  ems_main<<<GRID_WG, 512, 0, stream>>>(z_real, z_imag, memp, ptrv, ctrl,
                                        wv_r, wv_i, mtp,
                                        out_zr, out_zi, out_mem, out_ptr, cnt);
  ems_fin<<<1, 64, 0, stream>>>(cnt, out_sc);
}